// Round 2
// baseline (5608.399 us; speedup 1.0000x reference)
//
#include <hip/hip_runtime.h>
#include <math.h>

// ---------------------------------------------------------------------------
// ModelSpectral: hierarchical SAGEConv unpooling + MLP tail + QR(524288x2).
//
// Scheme: all conv outputs are stored PRE-tanh; every consumer applies tanhf.
// Per level l (5..0):
//   gather:   Q[i] = P[inv[i]]                       (pre-tanh copy)
//   deg:      deg[dst]+=1 ; invdeg = 1/max(deg,1)
//   conv:     agg[dst] += tanh(x[src])  (atomics)
//             out[i] = (agg[i]*invdeg[i])@Wl + tanh(x[i])@Wr + b   (in place)
// Tail: fused MLP (tanh on input) -> y[n,2] in d_out, + double-precision
// sums (||a||^2, a.b, ||b||^2) for LAPACK-convention Householder QR.
//
// R1 fix: mlp_kernel's h1/h2/h3 were runtime-indexed -> scratch spill
// (VGPR=64, 6.5 GB HBM traffic, 1.9 ms). Full unroll => register-resident.
// ---------------------------------------------------------------------------

static inline int imin(int a, int b) { return a < b ? a : b; }

__global__ void coarse_kernel(float* __restrict__ out, const float* __restrict__ Wl,
                              const float* __restrict__ Wr, const float* __restrict__ b) {
    int t = threadIdx.x;
    if (t < 64) {
        int i = t >> 5, c = t & 31;
        // x = eye(2); edges [[0,1],[1,0]]: agg[i] = x[1-i], deg=1
        out[i * 32 + c] = Wl[(1 ^ i) * 32 + c] + Wr[i * 32 + c] + b[c];  // pre-tanh
    }
}

__global__ void gather_kernel(float* __restrict__ out, const float* __restrict__ in,
                              const int* __restrict__ inv, int n) {
    int total = n * 32;
    int stride = gridDim.x * blockDim.x;
    for (int idx = blockIdx.x * blockDim.x + threadIdx.x; idx < total; idx += stride) {
        int i = idx >> 5, j = idx & 31;
        out[idx] = in[inv[i] * 32 + j];
    }
}

__global__ void deg_kernel(float* __restrict__ deg, const int* __restrict__ dst, int E) {
    int stride = gridDim.x * blockDim.x;
    for (int e = blockIdx.x * blockDim.x + threadIdx.x; e < E; e += stride)
        unsafeAtomicAdd(&deg[dst[e]], 1.0f);
}

__global__ void invdeg_kernel(float* __restrict__ deg, int n) {
    int stride = gridDim.x * blockDim.x;
    for (int i = blockIdx.x * blockDim.x + threadIdx.x; i < n; i += stride)
        deg[i] = 1.0f / fmaxf(deg[i], 1.0f);
}

// agg[dst] += tanh(x[src]); 32 lanes per edge (lane j = feature j)
__global__ void scatter_kernel(float* __restrict__ agg, const float* __restrict__ x,
                               const int* __restrict__ edges, int E) {
    const int* __restrict__ src = edges;
    const int* __restrict__ dst = edges + E;
    int total = E * 32;
    int stride = gridDim.x * blockDim.x;
    for (int idx = blockIdx.x * blockDim.x + threadIdx.x; idx < total; idx += stride) {
        int e = idx >> 5, j = idx & 31;
        float v = tanhf(x[src[e] * 32 + j]);
        unsafeAtomicAdd(&agg[dst[e] * 32 + j], v);
    }
}

// in place: agg[i] <- (agg[i]*invdeg[i])@Wl + tanh(x[i])@Wr + b   (pre-tanh out)
__global__ void dense_kernel(float* __restrict__ agg, const float* __restrict__ x,
                             const float* __restrict__ invdeg,
                             const float* __restrict__ Wl, const float* __restrict__ Wr,
                             const float* __restrict__ b, int n) {
    __shared__ float sWl[1024], sWr[1024], sb[32];
    for (int t = threadIdx.x; t < 1024; t += blockDim.x) { sWl[t] = Wl[t]; sWr[t] = Wr[t]; }
    if (threadIdx.x < 32) sb[threadIdx.x] = b[threadIdx.x];
    __syncthreads();
    int row = blockIdx.x * 8 + (threadIdx.x >> 5);
    int c = threadIdx.x & 31;
    if (row >= n) return;
    float av = agg[row * 32 + c] * invdeg[row];
    float xv = tanhf(x[row * 32 + c]);
    float acc = sb[c];
#pragma unroll
    for (int k = 0; k < 32; ++k) {
        float a = __shfl(av, k, 32);
        float t = __shfl(xv, k, 32);
        acc += a * sWl[k * 32 + c] + t * sWr[k * 32 + c];
    }
    agg[row * 32 + c] = acc;
}

// fused MLP tail: y = tanh(tanh(tanh(tanh(x)W1+b1)W2+b2)W3+b3)Wf+bf
// also accumulate double sums: saa=sum(y0^2), sab=sum(y0*y1), sbb=sum(y1^2)
// ALL per-thread arrays statically indexed (full unroll) => register-resident.
__global__ void __launch_bounds__(256)
mlp_kernel(float* __restrict__ y, const float* __restrict__ x,
           const float* __restrict__ W1, const float* __restrict__ b1,
           const float* __restrict__ W2, const float* __restrict__ b2,
           const float* __restrict__ W3, const float* __restrict__ b3,
           const float* __restrict__ Wf, const float* __restrict__ bf,
           double* __restrict__ sums, int n) {
    __shared__ float sW1[512], sb1[16], sW2[512], sb2[32], sW3[1024], sb3[32], sWf[64], sbf[2];
    for (int t = threadIdx.x; t < 512; t += blockDim.x) { sW1[t] = W1[t]; sW2[t] = W2[t]; }
    for (int t = threadIdx.x; t < 1024; t += blockDim.x) sW3[t] = W3[t];
    if (threadIdx.x < 64) sWf[threadIdx.x] = Wf[threadIdx.x];
    if (threadIdx.x < 16) sb1[threadIdx.x] = b1[threadIdx.x];
    if (threadIdx.x < 32) { sb2[threadIdx.x] = b2[threadIdx.x]; sb3[threadIdx.x] = b3[threadIdx.x]; }
    if (threadIdx.x < 2) sbf[threadIdx.x] = bf[threadIdx.x];
    __syncthreads();

    double la = 0.0, lab = 0.0, lb = 0.0;
    int stride = gridDim.x * blockDim.x;
    for (int row = blockIdx.x * blockDim.x + threadIdx.x; row < n; row += stride) {
        const float4* xr = (const float4*)(x + row * 32);
        float xt[32];
#pragma unroll
        for (int q = 0; q < 8; ++q) {
            float4 v = xr[q];
            xt[q * 4 + 0] = tanhf(v.x);
            xt[q * 4 + 1] = tanhf(v.y);
            xt[q * 4 + 2] = tanhf(v.z);
            xt[q * 4 + 3] = tanhf(v.w);
        }
        float h1[16];
#pragma unroll
        for (int c = 0; c < 16; ++c) h1[c] = sb1[c];
#pragma unroll
        for (int k = 0; k < 32; ++k) {
            float t = xt[k];
#pragma unroll
            for (int c = 0; c < 16; ++c) h1[c] += t * sW1[k * 16 + c];
        }
        float h2[32];
#pragma unroll
        for (int c = 0; c < 32; ++c) h2[c] = sb2[c];
#pragma unroll
        for (int k = 0; k < 16; ++k) {
            float t = tanhf(h1[k]);
#pragma unroll
            for (int c = 0; c < 32; ++c) h2[c] += t * sW2[k * 32 + c];
        }
        float h3[32];
#pragma unroll
        for (int c = 0; c < 32; ++c) h3[c] = sb3[c];
#pragma unroll
        for (int k = 0; k < 32; ++k) {
            float t = tanhf(h2[k]);
#pragma unroll
            for (int c = 0; c < 32; ++c) h3[c] += t * sW3[k * 32 + c];
        }
        float y0 = sbf[0], y1 = sbf[1];
#pragma unroll
        for (int k = 0; k < 32; ++k) {
            float t = tanhf(h3[k]);
            y0 += t * sWf[k * 2];
            y1 += t * sWf[k * 2 + 1];
        }
        y[row * 2] = y0;
        y[row * 2 + 1] = y1;
        la += (double)y0 * (double)y0;
        lab += (double)y0 * (double)y1;
        lb += (double)y1 * (double)y1;
    }
    // wave (64) reduce, then block reduce, then one atomic per block
#pragma unroll
    for (int off = 32; off > 0; off >>= 1) {
        la += __shfl_down(la, off);
        lab += __shfl_down(lab, off);
        lb += __shfl_down(lb, off);
    }
    __shared__ double red[4][3];
    int wid = threadIdx.x >> 6;
    if ((threadIdx.x & 63) == 0) { red[wid][0] = la; red[wid][1] = lab; red[wid][2] = lb; }
    __syncthreads();
    if (threadIdx.x == 0) {
        double ta = 0, tb = 0, tc = 0;
        int nw = (blockDim.x + 63) / 64;
        for (int w = 0; w < nw; ++w) { ta += red[w][0]; tb += red[w][1]; tc += red[w][2]; }
        unsafeAtomicAdd(&sums[0], ta);
        unsafeAtomicAdd(&sums[1], tb);
        unsafeAtomicAdd(&sums[2], tc);
    }
}

// LAPACK (geqrf/orgqr) Householder sign convention for 2-column QR.
__global__ void qr_scalar_kernel(float* __restrict__ scal, const double* __restrict__ sums,
                                 const float* __restrict__ y) {
    double saa = sums[0], sab = sums[1], sbb = sums[2];
    double a0 = (double)y[0], b0 = (double)y[1];
    double a1 = (double)y[2], b1v = (double)y[3];
    double na = sqrt(saa);
    double beta1 = (a0 >= 0.0) ? -na : na;       // beta = -sign(alpha)*||a||
    double R12 = sab / beta1;                    // (H1 b)[0] = q1.b
    double v2 = sbb - R12 * R12;                 // ||b - R12 q1||^2
    if (v2 < 0.0) v2 = 0.0;
    double nb = sqrt(v2);
    double denom = a0 - beta1;                   // nonzero: a0 + sign(a0)||a||
    double tau1 = (beta1 - a0) / beta1;
    double u1b = b0 + (sab - a0 * b0) / denom;   // v1 . b  (v1[0]=1)
    double y1h = b1v - tau1 * u1b * (a1 / denom);// (H1 b)[1] -> pivot of reflector 2
    double beta2 = (y1h >= 0.0) ? -nb : nb;
    scal[0] = (float)(1.0 / beta1);
    scal[1] = (float)R12;
    scal[2] = (float)(1.0 / beta2);
}

__global__ void q_kernel(float* __restrict__ y, const float* __restrict__ scal, int n) {
    float invb1 = scal[0], R12 = scal[1], invb2 = scal[2];
    int stride = gridDim.x * blockDim.x;
    float2* p = (float2*)y;
    for (int i = blockIdx.x * blockDim.x + threadIdx.x; i < n; i += stride) {
        float2 v = p[i];
        float qa = v.x * invb1;
        float qb = (v.y - R12 * qa) * invb2;
        p[i] = make_float2(qa, qb);
    }
}

extern "C" void kernel_launch(void* const* d_in, const int* in_sizes, int n_in,
                              void* d_out, int out_size, void* d_ws, size_t ws_size,
                              hipStream_t stream) {
    const int* edges[6];
    const int* inv[6];
    int nl[6], El[6];
    for (int l = 0; l < 6; ++l) {
        edges[l] = (const int*)d_in[2 * l];
        inv[l] = (const int*)d_in[2 * l + 1];
        El[l] = in_sizes[2 * l] / 2;
        nl[l] = in_sizes[2 * l + 1];
    }
    const float* Wc_l = (const float*)d_in[13];
    const float* Wc_r = (const float*)d_in[14];
    const float* bc = (const float*)d_in[15];
    const float* Wp_l[2] = {(const float*)d_in[16], (const float*)d_in[19]};
    const float* Wp_r[2] = {(const float*)d_in[17], (const float*)d_in[20]};
    const float* bp[2] = {(const float*)d_in[18], (const float*)d_in[21]};
    const float* W1 = (const float*)d_in[22];
    const float* b1 = (const float*)d_in[23];
    const float* W2 = (const float*)d_in[24];
    const float* b2 = (const float*)d_in[25];
    const float* W3 = (const float*)d_in[26];
    const float* b3 = (const float*)d_in[27];
    const float* Wf = (const float*)d_in[28];
    const float* bf = (const float*)d_in[29];

    // workspace carve: bufA 64MB | bufB 64MB | deg 2MB | sums 24B | scal 12B
    char* ws = (char*)d_ws;
    float* bufA = (float*)ws;
    float* bufB = (float*)(ws + 67108864);
    float* deg = (float*)(ws + 134217728);
    double* sums = (double*)(ws + 136314880);
    float* scal = (float*)(ws + 136315008);

    float* P = bufA;  // holds previous-level pre-tanh result
    float* Q = bufB;
    coarse_kernel<<<1, 64, 0, stream>>>(P, Wc_l, Wc_r, bc);

    for (int l = 5; l >= 0; --l) {
        int n = nl[l], E = El[l];
        gather_kernel<<<imin((n * 32 + 255) / 256, 65536), 256, 0, stream>>>(Q, P, inv[l], n);
        hipMemsetAsync(deg, 0, (size_t)n * sizeof(float), stream);
        deg_kernel<<<imin((E + 255) / 256, 32768), 256, 0, stream>>>(deg, edges[l] + E, E);
        invdeg_kernel<<<imin((n + 255) / 256, 8192), 256, 0, stream>>>(deg, n);
        // conv1: agg in P, x in Q
        hipMemsetAsync(P, 0, (size_t)n * 32 * sizeof(float), stream);
        scatter_kernel<<<imin((E * 32 + 255) / 256, 65536), 256, 0, stream>>>(P, Q, edges[l], E);
        dense_kernel<<<(n + 7) / 8, 256, 0, stream>>>(P, Q, deg, Wp_l[0], Wp_r[0], bp[0], n);
        // conv2: agg in Q, x in P
        hipMemsetAsync(Q, 0, (size_t)n * 32 * sizeof(float), stream);
        scatter_kernel<<<imin((E * 32 + 255) / 256, 65536), 256, 0, stream>>>(Q, P, edges[l], E);
        dense_kernel<<<(n + 7) / 8, 256, 0, stream>>>(Q, P, deg, Wp_l[1], Wp_r[1], bp[1], n);
        float* t = P; P = Q; Q = t;
    }

    hipMemsetAsync(sums, 0, 3 * sizeof(double), stream);
    mlp_kernel<<<2048, 256, 0, stream>>>((float*)d_out, P, W1, b1, W2, b2, W3, b3, Wf, bf,
                                         sums, nl[0]);
    qr_scalar_kernel<<<1, 1, 0, stream>>>(scal, sums, (const float*)d_out);
    q_kernel<<<imin((nl[0] + 255) / 256, 4096), 256, 0, stream>>>((float*)d_out, scal, nl[0]);
}

// Round 3
// 3590.665 us; speedup vs baseline: 1.5619x; 1.5619x over previous
//
#include <hip/hip_runtime.h>
#include <math.h>

// ---------------------------------------------------------------------------
// ModelSpectral: hierarchical SAGEConv unpooling + MLP tail + QR(524288x2).
//
// R2 scheme change: all conv outputs stored POST-tanh (every consumer needs
// tanh, so apply once at producer write). Deletes per-edge tanh in scatter.
// Per level l (5..0):
//   gather:   Q[i] = P[inv[i]]                       (post-tanh copy)
//   deg:      deg[dst]+=1 ; invdeg = 1/max(deg,1)
//   conv:     agg[dst] += x[src]  (atomics, x already tanh'd)
//             out[i] = tanh((agg[i]*invdeg[i])@Wl + x[i]@Wr + b)   (in place)
// Tail: wave-parallel MLP (32 lanes per row, shfl broadcast — R1's
// thread-per-row version spilled 4KB/row to scratch) -> y[n,2] + double
// sums (||a||^2, a.b, ||b||^2) for LAPACK-convention Householder QR.
// ---------------------------------------------------------------------------

static inline int imin(int a, int b) { return a < b ? a : b; }

__global__ void coarse_kernel(float* __restrict__ out, const float* __restrict__ Wl,
                              const float* __restrict__ Wr, const float* __restrict__ b) {
    int t = threadIdx.x;
    if (t < 64) {
        int i = t >> 5, c = t & 31;
        // x = eye(2); edges [[0,1],[1,0]]: agg[i] = x[1-i], deg=1
        out[i * 32 + c] = tanhf(Wl[(1 ^ i) * 32 + c] + Wr[i * 32 + c] + b[c]);
    }
}

__global__ void gather_kernel(float* __restrict__ out, const float* __restrict__ in,
                              const int* __restrict__ inv, int n) {
    int total = n * 32;
    int stride = gridDim.x * blockDim.x;
    for (int idx = blockIdx.x * blockDim.x + threadIdx.x; idx < total; idx += stride) {
        int i = idx >> 5, j = idx & 31;
        out[idx] = in[inv[i] * 32 + j];
    }
}

__global__ void deg_kernel(float* __restrict__ deg, const int* __restrict__ dst, int E) {
    int stride = gridDim.x * blockDim.x;
    for (int e = blockIdx.x * blockDim.x + threadIdx.x; e < E; e += stride)
        unsafeAtomicAdd(&deg[dst[e]], 1.0f);
}

__global__ void invdeg_kernel(float* __restrict__ deg, int n) {
    int stride = gridDim.x * blockDim.x;
    for (int i = blockIdx.x * blockDim.x + threadIdx.x; i < n; i += stride)
        deg[i] = 1.0f / fmaxf(deg[i], 1.0f);
}

// agg[dst] += x[src]; 32 lanes per edge (lane j = feature j); x post-tanh
__global__ void scatter_kernel(float* __restrict__ agg, const float* __restrict__ x,
                               const int* __restrict__ edges, int E) {
    const int* __restrict__ src = edges;
    const int* __restrict__ dst = edges + E;
    int total = E * 32;
    int stride = gridDim.x * blockDim.x;
    for (int idx = blockIdx.x * blockDim.x + threadIdx.x; idx < total; idx += stride) {
        int e = idx >> 5, j = idx & 31;
        unsafeAtomicAdd(&agg[dst[e] * 32 + j], x[src[e] * 32 + j]);
    }
}

// in place: agg[i] <- tanh((agg[i]*invdeg[i])@Wl + x[i]@Wr + b)
__global__ void dense_kernel(float* __restrict__ agg, const float* __restrict__ x,
                             const float* __restrict__ invdeg,
                             const float* __restrict__ Wl, const float* __restrict__ Wr,
                             const float* __restrict__ b, int n) {
    __shared__ float sWl[1024], sWr[1024], sb[32];
    for (int t = threadIdx.x; t < 1024; t += blockDim.x) { sWl[t] = Wl[t]; sWr[t] = Wr[t]; }
    if (threadIdx.x < 32) sb[threadIdx.x] = b[threadIdx.x];
    __syncthreads();
    int row = blockIdx.x * 8 + (threadIdx.x >> 5);
    int c = threadIdx.x & 31;
    if (row >= n) return;
    float av = agg[row * 32 + c] * invdeg[row];
    float xv = x[row * 32 + c];
    float acc = sb[c];
#pragma unroll
    for (int k = 0; k < 32; ++k) {
        float a = __shfl(av, k, 32);
        float t = __shfl(xv, k, 32);
        acc += a * sWl[k * 32 + c] + t * sWr[k * 32 + c];
    }
    agg[row * 32 + c] = tanhf(acc);
}

// Wave-parallel fused MLP tail: 32 lanes per row, lane c owns feature c.
// x is already post-tanh. y = tanh(tanh(tanh(x@W1+b1)@W2+b2)@W3+b3)@Wf+bf
// + double sums (saa, sab, sbb) for QR.
__global__ void __launch_bounds__(256)
mlp_kernel(float* __restrict__ y, const float* __restrict__ x,
           const float* __restrict__ W1, const float* __restrict__ b1,
           const float* __restrict__ W2, const float* __restrict__ b2,
           const float* __restrict__ W3, const float* __restrict__ b3,
           const float* __restrict__ Wf, const float* __restrict__ bf,
           double* __restrict__ sums, int n) {
    __shared__ float sW1[512], sb1[16], sW2[512], sb2[32], sW3[1024], sb3[32], sWf[64], sbf[2];
    for (int t = threadIdx.x; t < 512; t += blockDim.x) { sW1[t] = W1[t]; sW2[t] = W2[t]; }
    for (int t = threadIdx.x; t < 1024; t += blockDim.x) sW3[t] = W3[t];
    if (threadIdx.x < 64) sWf[threadIdx.x] = Wf[threadIdx.x];
    if (threadIdx.x < 16) sb1[threadIdx.x] = b1[threadIdx.x];
    if (threadIdx.x < 32) { sb2[threadIdx.x] = b2[threadIdx.x]; sb3[threadIdx.x] = b3[threadIdx.x]; }
    if (threadIdx.x < 2) sbf[threadIdx.x] = bf[threadIdx.x];
    __syncthreads();

    int lane = threadIdx.x & 31;
    int grp = threadIdx.x >> 5;           // 8 row-groups per block
    double la = 0.0, lab = 0.0, lb = 0.0;
    int rstride = gridDim.x * 8;
    for (int row = blockIdx.x * 8 + grp; row < n; row += rstride) {
        float xv = x[row * 32 + lane];    // post-tanh, coalesced
        // layer1: 32->16 (lanes 16..31 duplicate lanes 0..15)
        float h1 = sb1[lane & 15];
#pragma unroll
        for (int k = 0; k < 32; ++k)
            h1 += __shfl(xv, k, 32) * sW1[k * 16 + (lane & 15)];
        float t1 = tanhf(h1);
        // layer2: 16->32
        float h2 = sb2[lane];
#pragma unroll
        for (int k = 0; k < 16; ++k)
            h2 += __shfl(t1, k, 32) * sW2[k * 32 + lane];
        float t2 = tanhf(h2);
        // layer3: 32->32
        float h3 = sb3[lane];
#pragma unroll
        for (int k = 0; k < 32; ++k)
            h3 += __shfl(t2, k, 32) * sW3[k * 32 + lane];
        float t3 = tanhf(h3);
        // final: 32->2, xor-reduce partial products across the 32-group
        float p0 = t3 * sWf[lane * 2];
        float p1 = t3 * sWf[lane * 2 + 1];
#pragma unroll
        for (int off = 16; off > 0; off >>= 1) {
            p0 += __shfl_xor(p0, off, 32);
            p1 += __shfl_xor(p1, off, 32);
        }
        if (lane == 0) {
            float y0 = p0 + sbf[0], y1 = p1 + sbf[1];
            y[row * 2] = y0;
            y[row * 2 + 1] = y1;
            la += (double)y0 * (double)y0;
            lab += (double)y0 * (double)y1;
            lb += (double)y1 * (double)y1;
        }
    }
    // wave (64) reduce, then block reduce, then one atomic per block
#pragma unroll
    for (int off = 32; off > 0; off >>= 1) {
        la += __shfl_down(la, off);
        lab += __shfl_down(lab, off);
        lb += __shfl_down(lb, off);
    }
    __shared__ double red[4][3];
    int wid = threadIdx.x >> 6;
    if ((threadIdx.x & 63) == 0) { red[wid][0] = la; red[wid][1] = lab; red[wid][2] = lb; }
    __syncthreads();
    if (threadIdx.x == 0) {
        double ta = 0, tb = 0, tc = 0;
        for (int w = 0; w < 4; ++w) { ta += red[w][0]; tb += red[w][1]; tc += red[w][2]; }
        unsafeAtomicAdd(&sums[0], ta);
        unsafeAtomicAdd(&sums[1], tb);
        unsafeAtomicAdd(&sums[2], tc);
    }
}

// LAPACK (geqrf/orgqr) Householder sign convention for 2-column QR.
__global__ void qr_scalar_kernel(float* __restrict__ scal, const double* __restrict__ sums,
                                 const float* __restrict__ y) {
    double saa = sums[0], sab = sums[1], sbb = sums[2];
    double a0 = (double)y[0], b0 = (double)y[1];
    double a1 = (double)y[2], b1v = (double)y[3];
    double na = sqrt(saa);
    double beta1 = (a0 >= 0.0) ? -na : na;       // beta = -sign(alpha)*||a||
    double R12 = sab / beta1;                    // (H1 b)[0] = q1.b
    double v2 = sbb - R12 * R12;                 // ||b - R12 q1||^2
    if (v2 < 0.0) v2 = 0.0;
    double nb = sqrt(v2);
    double denom = a0 - beta1;                   // nonzero: a0 + sign(a0)||a||
    double tau1 = (beta1 - a0) / beta1;
    double u1b = b0 + (sab - a0 * b0) / denom;   // v1 . b  (v1[0]=1)
    double y1h = b1v - tau1 * u1b * (a1 / denom);// (H1 b)[1] -> pivot of reflector 2
    double beta2 = (y1h >= 0.0) ? -nb : nb;
    scal[0] = (float)(1.0 / beta1);
    scal[1] = (float)R12;
    scal[2] = (float)(1.0 / beta2);
}

__global__ void q_kernel(float* __restrict__ y, const float* __restrict__ scal, int n) {
    float invb1 = scal[0], R12 = scal[1], invb2 = scal[2];
    int stride = gridDim.x * blockDim.x;
    float2* p = (float2*)y;
    for (int i = blockIdx.x * blockDim.x + threadIdx.x; i < n; i += stride) {
        float2 v = p[i];
        float qa = v.x * invb1;
        float qb = (v.y - R12 * qa) * invb2;
        p[i] = make_float2(qa, qb);
    }
}

extern "C" void kernel_launch(void* const* d_in, const int* in_sizes, int n_in,
                              void* d_out, int out_size, void* d_ws, size_t ws_size,
                              hipStream_t stream) {
    const int* edges[6];
    const int* inv[6];
    int nl[6], El[6];
    for (int l = 0; l < 6; ++l) {
        edges[l] = (const int*)d_in[2 * l];
        inv[l] = (const int*)d_in[2 * l + 1];
        El[l] = in_sizes[2 * l] / 2;
        nl[l] = in_sizes[2 * l + 1];
    }
    const float* Wc_l = (const float*)d_in[13];
    const float* Wc_r = (const float*)d_in[14];
    const float* bc = (const float*)d_in[15];
    const float* Wp_l[2] = {(const float*)d_in[16], (const float*)d_in[19]};
    const float* Wp_r[2] = {(const float*)d_in[17], (const float*)d_in[20]};
    const float* bp[2] = {(const float*)d_in[18], (const float*)d_in[21]};
    const float* W1 = (const float*)d_in[22];
    const float* b1 = (const float*)d_in[23];
    const float* W2 = (const float*)d_in[24];
    const float* b2 = (const float*)d_in[25];
    const float* W3 = (const float*)d_in[26];
    const float* b3 = (const float*)d_in[27];
    const float* Wf = (const float*)d_in[28];
    const float* bf = (const float*)d_in[29];

    // workspace carve: bufA 64MB | bufB 64MB | deg 2MB | sums 24B | scal 12B
    char* ws = (char*)d_ws;
    float* bufA = (float*)ws;
    float* bufB = (float*)(ws + 67108864);
    float* deg = (float*)(ws + 134217728);
    double* sums = (double*)(ws + 136314880);
    float* scal = (float*)(ws + 136315008);

    float* P = bufA;  // holds previous-level post-tanh result
    float* Q = bufB;
    coarse_kernel<<<1, 64, 0, stream>>>(P, Wc_l, Wc_r, bc);

    for (int l = 5; l >= 0; --l) {
        int n = nl[l], E = El[l];
        gather_kernel<<<imin((n * 32 + 255) / 256, 65536), 256, 0, stream>>>(Q, P, inv[l], n);
        hipMemsetAsync(deg, 0, (size_t)n * sizeof(float), stream);
        deg_kernel<<<imin((E + 255) / 256, 32768), 256, 0, stream>>>(deg, edges[l] + E, E);
        invdeg_kernel<<<imin((n + 255) / 256, 8192), 256, 0, stream>>>(deg, n);
        // conv1: agg in P, x in Q
        hipMemsetAsync(P, 0, (size_t)n * 32 * sizeof(float), stream);
        scatter_kernel<<<imin((E * 32 + 255) / 256, 65536), 256, 0, stream>>>(P, Q, edges[l], E);
        dense_kernel<<<(n + 7) / 8, 256, 0, stream>>>(P, Q, deg, Wp_l[0], Wp_r[0], bp[0], n);
        // conv2: agg in Q, x in P
        hipMemsetAsync(Q, 0, (size_t)n * 32 * sizeof(float), stream);
        scatter_kernel<<<imin((E * 32 + 255) / 256, 65536), 256, 0, stream>>>(Q, P, edges[l], E);
        dense_kernel<<<(n + 7) / 8, 256, 0, stream>>>(Q, P, deg, Wp_l[1], Wp_r[1], bp[1], n);
        float* t = P; P = Q; Q = t;
    }

    hipMemsetAsync(sums, 0, 3 * sizeof(double), stream);
    mlp_kernel<<<4096, 256, 0, stream>>>((float*)d_out, P, W1, b1, W2, b2, W3, b3, Wf, bf,
                                         sums, nl[0]);
    qr_scalar_kernel<<<1, 1, 0, stream>>>(scal, sums, (const float*)d_out);
    q_kernel<<<imin((nl[0] + 255) / 256, 4096), 256, 0, stream>>>((float*)d_out, scal, nl[0]);
}

// Round 5
// 3543.455 us; speedup vs baseline: 1.5827x; 1.0133x over previous
//
#include <hip/hip_runtime.h>
#include <math.h>

// ---------------------------------------------------------------------------
// ModelSpectral: hierarchical SAGEConv unpooling + MLP tail + QR(524288x2).
//
// R3: scatter_kernel hit the f32-atomic issue ceiling (268M atomics @ 323G/s
// per conv). Replace with on-device CSR (hist -> scan -> fill, int atomics
// only, 32x fewer) + fused pull-aggregation conv (register agg + mean +
// dense + tanh in one pass; deletes agg memset + separate dense kernel).
// CSR built once per level, used by both convs. Falls back to the R2
// atomic-scatter path if ws_size < ~170MB.
//
// All conv outputs stored POST-tanh (every consumer applies tanh -> producer
// applies it once).
//
// R4: resubmission of R3 unchanged (bench never ran: acquisition timeout).
// ---------------------------------------------------------------------------

static inline int imin(int a, int b) { return a < b ? a : b; }

__global__ void coarse_kernel(float* __restrict__ out, const float* __restrict__ Wl,
                              const float* __restrict__ Wr, const float* __restrict__ b) {
    int t = threadIdx.x;
    if (t < 64) {
        int i = t >> 5, c = t & 31;
        // x = eye(2); edges [[0,1],[1,0]]: agg[i] = x[1-i], deg=1
        out[i * 32 + c] = tanhf(Wl[(1 ^ i) * 32 + c] + Wr[i * 32 + c] + b[c]);
    }
}

__global__ void gather_kernel(float* __restrict__ out, const float* __restrict__ in,
                              const int* __restrict__ inv, int n) {
    int total = n * 32;
    int stride = gridDim.x * blockDim.x;
    for (int idx = blockIdx.x * blockDim.x + threadIdx.x; idx < total; idx += stride) {
        int i = idx >> 5, j = idx & 31;
        out[idx] = in[inv[i] * 32 + j];
    }
}

// ---------------- CSR build ----------------
__global__ void hist_kernel(int* __restrict__ cnt, const int* __restrict__ dst, int E) {
    int stride = gridDim.x * blockDim.x;
    for (int e = blockIdx.x * blockDim.x + threadIdx.x; e < E; e += stride)
        atomicAdd(&cnt[dst[e]], 1);
}

// exclusive scan, 1024 elems per block (Hillis-Steele in LDS)
__global__ void scan1_kernel(int* __restrict__ a, int* __restrict__ part, int n) {
    __shared__ int s[1024];
    int t = threadIdx.x, i = blockIdx.x * 1024 + t;
    int v = (i < n) ? a[i] : 0;
    s[t] = v;
    __syncthreads();
    for (int off = 1; off < 1024; off <<= 1) {
        int add = (t >= off) ? s[t - off] : 0;
        __syncthreads();
        s[t] += add;
        __syncthreads();
    }
    if (i < n) a[i] = s[t] - v;             // exclusive
    if (t == 1023) part[blockIdx.x] = s[t]; // block total
}

__global__ void scan2_kernel(int* __restrict__ part, int nb) {
    __shared__ int s[1024];
    int t = threadIdx.x;
    int v = (t < nb) ? part[t] : 0;
    s[t] = v;
    __syncthreads();
    for (int off = 1; off < 1024; off <<= 1) {
        int add = (t >= off) ? s[t - off] : 0;
        __syncthreads();
        s[t] += add;
        __syncthreads();
    }
    if (t < nb) part[t] = s[t] - v;         // exclusive
}

__global__ void scan3_kernel(int* __restrict__ a, const int* __restrict__ part, int n) {
    int i = blockIdx.x * 1024 + threadIdx.x;
    if (i < n && blockIdx.x > 0) a[i] += part[blockIdx.x];
}

// fill: off[d] currently = start(d); after fill off[d] = end(d)
__global__ void fill_kernel(int* __restrict__ off, int* __restrict__ csr,
                            const int* __restrict__ edges, int E) {
    const int* __restrict__ src = edges;
    const int* __restrict__ dst = edges + E;
    int stride = gridDim.x * blockDim.x;
    for (int e = blockIdx.x * blockDim.x + threadIdx.x; e < E; e += stride) {
        int p = atomicAdd(&off[dst[e]], 1);
        csr[p] = src[e];
    }
}

// fused conv: out[d] = tanh( mean_{s in csr[d]}(x[s]) @ Wl + x[d] @ Wr + b )
// 32 lanes per row (lane = feature), 8 rows per 256-thread block, grid-stride.
// Post-fill convention: range(d) = [ d? off[d-1] : 0 , off[d] ).
__global__ void __launch_bounds__(256)
conv_csr_kernel(float* __restrict__ out, const float* __restrict__ x,
                const int* __restrict__ csr, const int* __restrict__ off,
                const float* __restrict__ Wl, const float* __restrict__ Wr,
                const float* __restrict__ b, int n) {
    __shared__ float sWl[1024], sWr[1024], sb[32];
    for (int t = threadIdx.x; t < 1024; t += blockDim.x) { sWl[t] = Wl[t]; sWr[t] = Wr[t]; }
    if (threadIdx.x < 32) sb[threadIdx.x] = b[threadIdx.x];
    __syncthreads();
    int lane = threadIdx.x & 31;
    int grp = threadIdx.x >> 5;
    int rstride = gridDim.x * 8;
    for (int row = blockIdx.x * 8 + grp; row < n; row += rstride) {
        int end = off[row];
        int start = (row == 0) ? 0 : off[row - 1];
        float acc = 0.f;
        for (int i = start; i < end; ++i) {
            int s = csr[i];
            acc += x[(size_t)s * 32 + lane];
        }
        float am = acc * (1.f / fmaxf((float)(end - start), 1.f));
        float xv = x[(size_t)row * 32 + lane];
        float o = sb[lane];
#pragma unroll
        for (int k = 0; k < 32; ++k) {
            float a = __shfl(am, k, 32);
            float t = __shfl(xv, k, 32);
            o += a * sWl[k * 32 + lane] + t * sWr[k * 32 + lane];
        }
        out[(size_t)row * 32 + lane] = tanhf(o);
    }
}

// ---------------- fallback (R2 atomic-scatter path) ----------------
__global__ void deg_kernel(float* __restrict__ deg, const int* __restrict__ dst, int E) {
    int stride = gridDim.x * blockDim.x;
    for (int e = blockIdx.x * blockDim.x + threadIdx.x; e < E; e += stride)
        unsafeAtomicAdd(&deg[dst[e]], 1.0f);
}

__global__ void invdeg_kernel(float* __restrict__ deg, int n) {
    int stride = gridDim.x * blockDim.x;
    for (int i = blockIdx.x * blockDim.x + threadIdx.x; i < n; i += stride)
        deg[i] = 1.0f / fmaxf(deg[i], 1.0f);
}

__global__ void scatter_kernel(float* __restrict__ agg, const float* __restrict__ x,
                               const int* __restrict__ edges, int E) {
    const int* __restrict__ src = edges;
    const int* __restrict__ dst = edges + E;
    int total = E * 32;
    int stride = gridDim.x * blockDim.x;
    for (int idx = blockIdx.x * blockDim.x + threadIdx.x; idx < total; idx += stride) {
        int e = idx >> 5, j = idx & 31;
        unsafeAtomicAdd(&agg[dst[e] * 32 + j], x[src[e] * 32 + j]);
    }
}

__global__ void dense_kernel(float* __restrict__ agg, const float* __restrict__ x,
                             const float* __restrict__ invdeg,
                             const float* __restrict__ Wl, const float* __restrict__ Wr,
                             const float* __restrict__ b, int n) {
    __shared__ float sWl[1024], sWr[1024], sb[32];
    for (int t = threadIdx.x; t < 1024; t += blockDim.x) { sWl[t] = Wl[t]; sWr[t] = Wr[t]; }
    if (threadIdx.x < 32) sb[threadIdx.x] = b[threadIdx.x];
    __syncthreads();
    int row = blockIdx.x * 8 + (threadIdx.x >> 5);
    int c = threadIdx.x & 31;
    if (row >= n) return;
    float av = agg[row * 32 + c] * invdeg[row];
    float xv = x[row * 32 + c];
    float acc = sb[c];
#pragma unroll
    for (int k = 0; k < 32; ++k) {
        float a = __shfl(av, k, 32);
        float t = __shfl(xv, k, 32);
        acc += a * sWl[k * 32 + c] + t * sWr[k * 32 + c];
    }
    agg[row * 32 + c] = tanhf(acc);
}

// ---------------- MLP tail + QR ----------------
// Wave-parallel fused MLP: 32 lanes per row, lane c owns feature c.
__global__ void __launch_bounds__(256)
mlp_kernel(float* __restrict__ y, const float* __restrict__ x,
           const float* __restrict__ W1, const float* __restrict__ b1,
           const float* __restrict__ W2, const float* __restrict__ b2,
           const float* __restrict__ W3, const float* __restrict__ b3,
           const float* __restrict__ Wf, const float* __restrict__ bf,
           double* __restrict__ sums, int n) {
    __shared__ float sW1[512], sb1[16], sW2[512], sb2[32], sW3[1024], sb3[32], sWf[64], sbf[2];
    for (int t = threadIdx.x; t < 512; t += blockDim.x) { sW1[t] = W1[t]; sW2[t] = W2[t]; }
    for (int t = threadIdx.x; t < 1024; t += blockDim.x) sW3[t] = W3[t];
    if (threadIdx.x < 64) sWf[threadIdx.x] = Wf[threadIdx.x];
    if (threadIdx.x < 16) sb1[threadIdx.x] = b1[threadIdx.x];
    if (threadIdx.x < 32) { sb2[threadIdx.x] = b2[threadIdx.x]; sb3[threadIdx.x] = b3[threadIdx.x]; }
    if (threadIdx.x < 2) sbf[threadIdx.x] = bf[threadIdx.x];
    __syncthreads();

    int lane = threadIdx.x & 31;
    int grp = threadIdx.x >> 5;
    double la = 0.0, lab = 0.0, lb = 0.0;
    int rstride = gridDim.x * 8;
    for (int row = blockIdx.x * 8 + grp; row < n; row += rstride) {
        float xv = x[(size_t)row * 32 + lane];
        float h1 = sb1[lane & 15];
#pragma unroll
        for (int k = 0; k < 32; ++k)
            h1 += __shfl(xv, k, 32) * sW1[k * 16 + (lane & 15)];
        float t1 = tanhf(h1);
        float h2 = sb2[lane];
#pragma unroll
        for (int k = 0; k < 16; ++k)
            h2 += __shfl(t1, k, 32) * sW2[k * 32 + lane];
        float t2 = tanhf(h2);
        float h3 = sb3[lane];
#pragma unroll
        for (int k = 0; k < 32; ++k)
            h3 += __shfl(t2, k, 32) * sW3[k * 32 + lane];
        float t3 = tanhf(h3);
        float p0 = t3 * sWf[lane * 2];
        float p1 = t3 * sWf[lane * 2 + 1];
#pragma unroll
        for (int off = 16; off > 0; off >>= 1) {
            p0 += __shfl_xor(p0, off, 32);
            p1 += __shfl_xor(p1, off, 32);
        }
        if (lane == 0) {
            float y0 = p0 + sbf[0], y1 = p1 + sbf[1];
            y[row * 2] = y0;
            y[row * 2 + 1] = y1;
            la += (double)y0 * (double)y0;
            lab += (double)y0 * (double)y1;
            lb += (double)y1 * (double)y1;
        }
    }
#pragma unroll
    for (int off = 32; off > 0; off >>= 1) {
        la += __shfl_down(la, off);
        lab += __shfl_down(lab, off);
        lb += __shfl_down(lb, off);
    }
    __shared__ double red[4][3];
    int wid = threadIdx.x >> 6;
    if ((threadIdx.x & 63) == 0) { red[wid][0] = la; red[wid][1] = lab; red[wid][2] = lb; }
    __syncthreads();
    if (threadIdx.x == 0) {
        double ta = 0, tb = 0, tc = 0;
        for (int w = 0; w < 4; ++w) { ta += red[w][0]; tb += red[w][1]; tc += red[w][2]; }
        unsafeAtomicAdd(&sums[0], ta);
        unsafeAtomicAdd(&sums[1], tb);
        unsafeAtomicAdd(&sums[2], tc);
    }
}

// LAPACK (geqrf/orgqr) Householder sign convention for 2-column QR.
__global__ void qr_scalar_kernel(float* __restrict__ scal, const double* __restrict__ sums,
                                 const float* __restrict__ y) {
    double saa = sums[0], sab = sums[1], sbb = sums[2];
    double a0 = (double)y[0], b0 = (double)y[1];
    double a1 = (double)y[2], b1v = (double)y[3];
    double na = sqrt(saa);
    double beta1 = (a0 >= 0.0) ? -na : na;       // beta = -sign(alpha)*||a||
    double R12 = sab / beta1;                    // (H1 b)[0] = q1.b
    double v2 = sbb - R12 * R12;                 // ||b - R12 q1||^2
    if (v2 < 0.0) v2 = 0.0;
    double nb = sqrt(v2);
    double denom = a0 - beta1;                   // nonzero: a0 + sign(a0)||a||
    double tau1 = (beta1 - a0) / beta1;
    double u1b = b0 + (sab - a0 * b0) / denom;   // v1 . b  (v1[0]=1)
    double y1h = b1v - tau1 * u1b * (a1 / denom);// (H1 b)[1] -> pivot of reflector 2
    double beta2 = (y1h >= 0.0) ? -nb : nb;
    scal[0] = (float)(1.0 / beta1);
    scal[1] = (float)R12;
    scal[2] = (float)(1.0 / beta2);
}

__global__ void q_kernel(float* __restrict__ y, const float* __restrict__ scal, int n) {
    float invb1 = scal[0], R12 = scal[1], invb2 = scal[2];
    int stride = gridDim.x * blockDim.x;
    float2* p = (float2*)y;
    for (int i = blockIdx.x * blockDim.x + threadIdx.x; i < n; i += stride) {
        float2 v = p[i];
        float qa = v.x * invb1;
        float qb = (v.y - R12 * qa) * invb2;
        p[i] = make_float2(qa, qb);
    }
}

extern "C" void kernel_launch(void* const* d_in, const int* in_sizes, int n_in,
                              void* d_out, int out_size, void* d_ws, size_t ws_size,
                              hipStream_t stream) {
    const int* edges[6];
    const int* inv[6];
    int nl[6], El[6];
    for (int l = 0; l < 6; ++l) {
        edges[l] = (const int*)d_in[2 * l];
        inv[l] = (const int*)d_in[2 * l + 1];
        El[l] = in_sizes[2 * l] / 2;
        nl[l] = in_sizes[2 * l + 1];
    }
    const float* Wc_l = (const float*)d_in[13];
    const float* Wc_r = (const float*)d_in[14];
    const float* bc = (const float*)d_in[15];
    const float* Wp_l[2] = {(const float*)d_in[16], (const float*)d_in[19]};
    const float* Wp_r[2] = {(const float*)d_in[17], (const float*)d_in[20]};
    const float* bp[2] = {(const float*)d_in[18], (const float*)d_in[21]};
    const float* W1 = (const float*)d_in[22];
    const float* b1 = (const float*)d_in[23];
    const float* W2 = (const float*)d_in[24];
    const float* b2 = (const float*)d_in[25];
    const float* W3 = (const float*)d_in[26];
    const float* b3 = (const float*)d_in[27];
    const float* Wf = (const float*)d_in[28];
    const float* bf = (const float*)d_in[29];

    char* ws = (char*)d_ws;
    // CSR path layout:
    //  bufA 64MB | bufB 64MB | csr 32MB(E0*4) | off 2MB+pad | part 4KB | sums | scal
    const size_t OFF_CSR = 134217728;
    const size_t OFF_OFF = 167772160;
    const size_t OFF_PART = 169869824;
    const size_t OFF_SUMS = 169873920;
    const size_t OFF_SCAL = 169873952;
    const size_t NEED_CSR = 169874432;

    bool use_csr = ws_size >= NEED_CSR;

    float* bufA = (float*)ws;
    float* bufB = (float*)(ws + 67108864);
    double* sums;
    float* scal;

    float* P = bufA;  // holds previous-level post-tanh result
    float* Q = bufB;
    coarse_kernel<<<1, 64, 0, stream>>>(P, Wc_l, Wc_r, bc);

    if (use_csr) {
        int* csr = (int*)(ws + OFF_CSR);
        int* off = (int*)(ws + OFF_OFF);
        int* part = (int*)(ws + OFF_PART);
        sums = (double*)(ws + OFF_SUMS);
        scal = (float*)(ws + OFF_SCAL);

        for (int l = 5; l >= 0; --l) {
            int n = nl[l], E = El[l];
            gather_kernel<<<imin((n * 32 + 255) / 256, 65536), 256, 0, stream>>>(Q, P, inv[l], n);
            // build CSR for this level (used by both convs)
            hipMemsetAsync(off, 0, (size_t)n * sizeof(int), stream);
            hist_kernel<<<imin((E + 255) / 256, 32768), 256, 0, stream>>>(off, edges[l] + E, E);
            int nb = (n + 1023) / 1024;
            scan1_kernel<<<nb, 1024, 0, stream>>>(off, part, n);
            scan2_kernel<<<1, 1024, 0, stream>>>(part, nb);
            scan3_kernel<<<nb, 1024, 0, stream>>>(off, part, n);
            fill_kernel<<<imin((E + 255) / 256, 32768), 256, 0, stream>>>(off, csr, edges[l], E);
            // conv1: x=Q -> out=P's buffer; conv2: x=out1 -> out=Q's buffer
            conv_csr_kernel<<<imin((n + 7) / 8, 8192), 256, 0, stream>>>(
                P, Q, csr, off, Wp_l[0], Wp_r[0], bp[0], n);
            conv_csr_kernel<<<imin((n + 7) / 8, 8192), 256, 0, stream>>>(
                Q, P, csr, off, Wp_l[1], Wp_r[1], bp[1], n);
            float* t = P; P = Q; Q = t;
        }
    } else {
        // fallback: R2 atomic-scatter path
        float* deg = (float*)(ws + 134217728);
        sums = (double*)(ws + 136314880);
        scal = (float*)(ws + 136315008);
        for (int l = 5; l >= 0; --l) {
            int n = nl[l], E = El[l];
            gather_kernel<<<imin((n * 32 + 255) / 256, 65536), 256, 0, stream>>>(Q, P, inv[l], n);
            hipMemsetAsync(deg, 0, (size_t)n * sizeof(float), stream);
            deg_kernel<<<imin((E + 255) / 256, 32768), 256, 0, stream>>>(deg, edges[l] + E, E);
            invdeg_kernel<<<imin((n + 255) / 256, 8192), 256, 0, stream>>>(deg, n);
            hipMemsetAsync(P, 0, (size_t)n * 32 * sizeof(float), stream);
            scatter_kernel<<<imin((E * 32 + 255) / 256, 65536), 256, 0, stream>>>(P, Q, edges[l], E);
            dense_kernel<<<(n + 7) / 8, 256, 0, stream>>>(P, Q, deg, Wp_l[0], Wp_r[0], bp[0], n);
            hipMemsetAsync(Q, 0, (size_t)n * 32 * sizeof(float), stream);
            scatter_kernel<<<imin((E * 32 + 255) / 256, 65536), 256, 0, stream>>>(Q, P, edges[l], E);
            dense_kernel<<<(n + 7) / 8, 256, 0, stream>>>(Q, P, deg, Wp_l[1], Wp_r[1], bp[1], n);
            float* t = P; P = Q; Q = t;
        }
    }

    hipMemsetAsync(sums, 0, 3 * sizeof(double), stream);
    mlp_kernel<<<4096, 256, 0, stream>>>((float*)d_out, P, W1, b1, W2, b2, W3, b3, Wf, bf,
                                         sums, nl[0]);
    qr_scalar_kernel<<<1, 1, 0, stream>>>(scal, sums, (const float*)d_out);
    q_kernel<<<imin((nl[0] + 255) / 256, 4096), 256, 0, stream>>>((float*)d_out, scal, nl[0]);
}

// Round 6
// 2646.393 us; speedup vs baseline: 2.1193x; 1.3390x over previous
//
#include <hip/hip_runtime.h>
#include <math.h>

// ---------------------------------------------------------------------------
// ModelSpectral: hierarchical SAGEConv unpooling + MLP tail + QR(524288x2).
//
// R3: scatter hit the f32-atomic issue ceiling -> on-device CSR (hist/scan/
// fill) + fused pull-aggregation conv. R5 counters: conv_csr 803us,
// VALUBusy 14%, HBM 10%, occ 42% => LATENCY-bound on the serial
// csr[i] -> x[s] dependent-load chain (runtime trip count, no unroll).
//
// R5 fix: 8-way software-pipelined neighbor loop (8 csr indices, then 8
// independent x loads in flight) -> ~8x memory-level parallelism per row.
//
// All conv outputs stored POST-tanh (every consumer applies tanh -> producer
// applies it once). Falls back to the R2 atomic-scatter path if ws too small.
// ---------------------------------------------------------------------------

static inline int imin(int a, int b) { return a < b ? a : b; }

__global__ void coarse_kernel(float* __restrict__ out, const float* __restrict__ Wl,
                              const float* __restrict__ Wr, const float* __restrict__ b) {
    int t = threadIdx.x;
    if (t < 64) {
        int i = t >> 5, c = t & 31;
        // x = eye(2); edges [[0,1],[1,0]]: agg[i] = x[1-i], deg=1
        out[i * 32 + c] = tanhf(Wl[(1 ^ i) * 32 + c] + Wr[i * 32 + c] + b[c]);
    }
}

__global__ void gather_kernel(float* __restrict__ out, const float* __restrict__ in,
                              const int* __restrict__ inv, int n) {
    int total = n * 32;
    int stride = gridDim.x * blockDim.x;
    for (int idx = blockIdx.x * blockDim.x + threadIdx.x; idx < total; idx += stride) {
        int i = idx >> 5, j = idx & 31;
        out[idx] = in[inv[i] * 32 + j];
    }
}

// ---------------- CSR build ----------------
__global__ void hist_kernel(int* __restrict__ cnt, const int* __restrict__ dst, int E) {
    int stride = gridDim.x * blockDim.x;
    for (int e = blockIdx.x * blockDim.x + threadIdx.x; e < E; e += stride)
        atomicAdd(&cnt[dst[e]], 1);
}

// exclusive scan, 1024 elems per block (Hillis-Steele in LDS)
__global__ void scan1_kernel(int* __restrict__ a, int* __restrict__ part, int n) {
    __shared__ int s[1024];
    int t = threadIdx.x, i = blockIdx.x * 1024 + t;
    int v = (i < n) ? a[i] : 0;
    s[t] = v;
    __syncthreads();
    for (int off = 1; off < 1024; off <<= 1) {
        int add = (t >= off) ? s[t - off] : 0;
        __syncthreads();
        s[t] += add;
        __syncthreads();
    }
    if (i < n) a[i] = s[t] - v;             // exclusive
    if (t == 1023) part[blockIdx.x] = s[t]; // block total
}

__global__ void scan2_kernel(int* __restrict__ part, int nb) {
    __shared__ int s[1024];
    int t = threadIdx.x;
    int v = (t < nb) ? part[t] : 0;
    s[t] = v;
    __syncthreads();
    for (int off = 1; off < 1024; off <<= 1) {
        int add = (t >= off) ? s[t - off] : 0;
        __syncthreads();
        s[t] += add;
        __syncthreads();
    }
    if (t < nb) part[t] = s[t] - v;         // exclusive
}

__global__ void scan3_kernel(int* __restrict__ a, const int* __restrict__ part, int n) {
    int i = blockIdx.x * 1024 + threadIdx.x;
    if (i < n && blockIdx.x > 0) a[i] += part[blockIdx.x];
}

// fill: off[d] currently = start(d); after fill off[d] = end(d)
__global__ void fill_kernel(int* __restrict__ off, int* __restrict__ csr,
                            const int* __restrict__ edges, int E) {
    const int* __restrict__ src = edges;
    const int* __restrict__ dst = edges + E;
    int stride = gridDim.x * blockDim.x;
    for (int e = blockIdx.x * blockDim.x + threadIdx.x; e < E; e += stride) {
        int p = atomicAdd(&off[dst[e]], 1);
        csr[p] = src[e];
    }
}

// fused conv: out[d] = tanh( mean_{s in csr[d]}(x[s]) @ Wl + x[d] @ Wr + b )
// 32 lanes per row (lane = feature), 8 rows per 256-thread block, grid-stride.
// Post-fill convention: range(d) = [ d? off[d-1] : 0 , off[d] ).
// Neighbor loop 8-way software-pipelined: 8 csr index loads (consecutive ->
// dwordx4 pairs), then 8 INDEPENDENT x row loads in flight, then reduce.
__global__ void __launch_bounds__(256)
conv_csr_kernel(float* __restrict__ out, const float* __restrict__ x,
                const int* __restrict__ csr, const int* __restrict__ off,
                const float* __restrict__ Wl, const float* __restrict__ Wr,
                const float* __restrict__ b, int n) {
    __shared__ float sWl[1024], sWr[1024], sb[32];
    for (int t = threadIdx.x; t < 1024; t += blockDim.x) { sWl[t] = Wl[t]; sWr[t] = Wr[t]; }
    if (threadIdx.x < 32) sb[threadIdx.x] = b[threadIdx.x];
    __syncthreads();
    int lane = threadIdx.x & 31;
    int grp = threadIdx.x >> 5;
    int rstride = gridDim.x * 8;
    for (int row = blockIdx.x * 8 + grp; row < n; row += rstride) {
        int end = off[row];
        int start = (row == 0) ? 0 : off[row - 1];
        float acc = 0.f;
        int i = start;
        // 8-way pipelined main chunk
        for (; i + 8 <= end; i += 8) {
            int s0 = csr[i + 0], s1 = csr[i + 1], s2 = csr[i + 2], s3 = csr[i + 3];
            int s4 = csr[i + 4], s5 = csr[i + 5], s6 = csr[i + 6], s7 = csr[i + 7];
            float v0 = x[(size_t)s0 * 32 + lane];
            float v1 = x[(size_t)s1 * 32 + lane];
            float v2 = x[(size_t)s2 * 32 + lane];
            float v3 = x[(size_t)s3 * 32 + lane];
            float v4 = x[(size_t)s4 * 32 + lane];
            float v5 = x[(size_t)s5 * 32 + lane];
            float v6 = x[(size_t)s6 * 32 + lane];
            float v7 = x[(size_t)s7 * 32 + lane];
            acc += ((v0 + v1) + (v2 + v3)) + ((v4 + v5) + (v6 + v7));
        }
        // 2-way tail
        for (; i + 2 <= end; i += 2) {
            int s0 = csr[i], s1 = csr[i + 1];
            float v0 = x[(size_t)s0 * 32 + lane];
            float v1 = x[(size_t)s1 * 32 + lane];
            acc += v0 + v1;
        }
        if (i < end) acc += x[(size_t)csr[i] * 32 + lane];

        float am = acc * (1.f / fmaxf((float)(end - start), 1.f));
        float xv = x[(size_t)row * 32 + lane];
        float o = sb[lane];
#pragma unroll
        for (int k = 0; k < 32; ++k) {
            float a = __shfl(am, k, 32);
            float t = __shfl(xv, k, 32);
            o += a * sWl[k * 32 + lane] + t * sWr[k * 32 + lane];
        }
        out[(size_t)row * 32 + lane] = tanhf(o);
    }
}

// ---------------- fallback (R2 atomic-scatter path) ----------------
__global__ void deg_kernel(float* __restrict__ deg, const int* __restrict__ dst, int E) {
    int stride = gridDim.x * blockDim.x;
    for (int e = blockIdx.x * blockDim.x + threadIdx.x; e < E; e += stride)
        unsafeAtomicAdd(&deg[dst[e]], 1.0f);
}

__global__ void invdeg_kernel(float* __restrict__ deg, int n) {
    int stride = gridDim.x * blockDim.x;
    for (int i = blockIdx.x * blockDim.x + threadIdx.x; i < n; i += stride)
        deg[i] = 1.0f / fmaxf(deg[i], 1.0f);
}

__global__ void scatter_kernel(float* __restrict__ agg, const float* __restrict__ x,
                               const int* __restrict__ edges, int E) {
    const int* __restrict__ src = edges;
    const int* __restrict__ dst = edges + E;
    int total = E * 32;
    int stride = gridDim.x * blockDim.x;
    for (int idx = blockIdx.x * blockDim.x + threadIdx.x; idx < total; idx += stride) {
        int e = idx >> 5, j = idx & 31;
        unsafeAtomicAdd(&agg[dst[e] * 32 + j], x[src[e] * 32 + j]);
    }
}

__global__ void dense_kernel(float* __restrict__ agg, const float* __restrict__ x,
                             const float* __restrict__ invdeg,
                             const float* __restrict__ Wl, const float* __restrict__ Wr,
                             const float* __restrict__ b, int n) {
    __shared__ float sWl[1024], sWr[1024], sb[32];
    for (int t = threadIdx.x; t < 1024; t += blockDim.x) { sWl[t] = Wl[t]; sWr[t] = Wr[t]; }
    if (threadIdx.x < 32) sb[threadIdx.x] = b[threadIdx.x];
    __syncthreads();
    int row = blockIdx.x * 8 + (threadIdx.x >> 5);
    int c = threadIdx.x & 31;
    if (row >= n) return;
    float av = agg[row * 32 + c] * invdeg[row];
    float xv = x[row * 32 + c];
    float acc = sb[c];
#pragma unroll
    for (int k = 0; k < 32; ++k) {
        float a = __shfl(av, k, 32);
        float t = __shfl(xv, k, 32);
        acc += a * sWl[k * 32 + c] + t * sWr[k * 32 + c];
    }
    agg[row * 32 + c] = tanhf(acc);
}

// ---------------- MLP tail + QR ----------------
// Wave-parallel fused MLP: 32 lanes per row, lane c owns feature c.
__global__ void __launch_bounds__(256)
mlp_kernel(float* __restrict__ y, const float* __restrict__ x,
           const float* __restrict__ W1, const float* __restrict__ b1,
           const float* __restrict__ W2, const float* __restrict__ b2,
           const float* __restrict__ W3, const float* __restrict__ b3,
           const float* __restrict__ Wf, const float* __restrict__ bf,
           double* __restrict__ sums, int n) {
    __shared__ float sW1[512], sb1[16], sW2[512], sb2[32], sW3[1024], sb3[32], sWf[64], sbf[2];
    for (int t = threadIdx.x; t < 512; t += blockDim.x) { sW1[t] = W1[t]; sW2[t] = W2[t]; }
    for (int t = threadIdx.x; t < 1024; t += blockDim.x) sW3[t] = W3[t];
    if (threadIdx.x < 64) sWf[threadIdx.x] = Wf[threadIdx.x];
    if (threadIdx.x < 16) sb1[threadIdx.x] = b1[threadIdx.x];
    if (threadIdx.x < 32) { sb2[threadIdx.x] = b2[threadIdx.x]; sb3[threadIdx.x] = b3[threadIdx.x]; }
    if (threadIdx.x < 2) sbf[threadIdx.x] = bf[threadIdx.x];
    __syncthreads();

    int lane = threadIdx.x & 31;
    int grp = threadIdx.x >> 5;
    double la = 0.0, lab = 0.0, lb = 0.0;
    int rstride = gridDim.x * 8;
    for (int row = blockIdx.x * 8 + grp; row < n; row += rstride) {
        float xv = x[(size_t)row * 32 + lane];
        float h1 = sb1[lane & 15];
#pragma unroll
        for (int k = 0; k < 32; ++k)
            h1 += __shfl(xv, k, 32) * sW1[k * 16 + (lane & 15)];
        float t1 = tanhf(h1);
        float h2 = sb2[lane];
#pragma unroll
        for (int k = 0; k < 16; ++k)
            h2 += __shfl(t1, k, 32) * sW2[k * 32 + lane];
        float t2 = tanhf(h2);
        float h3 = sb3[lane];
#pragma unroll
        for (int k = 0; k < 32; ++k)
            h3 += __shfl(t2, k, 32) * sW3[k * 32 + lane];
        float t3 = tanhf(h3);
        float p0 = t3 * sWf[lane * 2];
        float p1 = t3 * sWf[lane * 2 + 1];
#pragma unroll
        for (int off = 16; off > 0; off >>= 1) {
            p0 += __shfl_xor(p0, off, 32);
            p1 += __shfl_xor(p1, off, 32);
        }
        if (lane == 0) {
            float y0 = p0 + sbf[0], y1 = p1 + sbf[1];
            y[row * 2] = y0;
            y[row * 2 + 1] = y1;
            la += (double)y0 * (double)y0;
            lab += (double)y0 * (double)y1;
            lb += (double)y1 * (double)y1;
        }
    }
#pragma unroll
    for (int off = 32; off > 0; off >>= 1) {
        la += __shfl_down(la, off);
        lab += __shfl_down(lab, off);
        lb += __shfl_down(lb, off);
    }
    __shared__ double red[4][3];
    int wid = threadIdx.x >> 6;
    if ((threadIdx.x & 63) == 0) { red[wid][0] = la; red[wid][1] = lab; red[wid][2] = lb; }
    __syncthreads();
    if (threadIdx.x == 0) {
        double ta = 0, tb = 0, tc = 0;
        for (int w = 0; w < 4; ++w) { ta += red[w][0]; tb += red[w][1]; tc += red[w][2]; }
        unsafeAtomicAdd(&sums[0], ta);
        unsafeAtomicAdd(&sums[1], tb);
        unsafeAtomicAdd(&sums[2], tc);
    }
}

// LAPACK (geqrf/orgqr) Householder sign convention for 2-column QR.
__global__ void qr_scalar_kernel(float* __restrict__ scal, const double* __restrict__ sums,
                                 const float* __restrict__ y) {
    double saa = sums[0], sab = sums[1], sbb = sums[2];
    double a0 = (double)y[0], b0 = (double)y[1];
    double a1 = (double)y[2], b1v = (double)y[3];
    double na = sqrt(saa);
    double beta1 = (a0 >= 0.0) ? -na : na;       // beta = -sign(alpha)*||a||
    double R12 = sab / beta1;                    // (H1 b)[0] = q1.b
    double v2 = sbb - R12 * R12;                 // ||b - R12 q1||^2
    if (v2 < 0.0) v2 = 0.0;
    double nb = sqrt(v2);
    double denom = a0 - beta1;                   // nonzero: a0 + sign(a0)||a||
    double tau1 = (beta1 - a0) / beta1;
    double u1b = b0 + (sab - a0 * b0) / denom;   // v1 . b  (v1[0]=1)
    double y1h = b1v - tau1 * u1b * (a1 / denom);// (H1 b)[1] -> pivot of reflector 2
    double beta2 = (y1h >= 0.0) ? -nb : nb;
    scal[0] = (float)(1.0 / beta1);
    scal[1] = (float)R12;
    scal[2] = (float)(1.0 / beta2);
}

__global__ void q_kernel(float* __restrict__ y, const float* __restrict__ scal, int n) {
    float invb1 = scal[0], R12 = scal[1], invb2 = scal[2];
    int stride = gridDim.x * blockDim.x;
    float2* p = (float2*)y;
    for (int i = blockIdx.x * blockDim.x + threadIdx.x; i < n; i += stride) {
        float2 v = p[i];
        float qa = v.x * invb1;
        float qb = (v.y - R12 * qa) * invb2;
        p[i] = make_float2(qa, qb);
    }
}

extern "C" void kernel_launch(void* const* d_in, const int* in_sizes, int n_in,
                              void* d_out, int out_size, void* d_ws, size_t ws_size,
                              hipStream_t stream) {
    const int* edges[6];
    const int* inv[6];
    int nl[6], El[6];
    for (int l = 0; l < 6; ++l) {
        edges[l] = (const int*)d_in[2 * l];
        inv[l] = (const int*)d_in[2 * l + 1];
        El[l] = in_sizes[2 * l] / 2;
        nl[l] = in_sizes[2 * l + 1];
    }
    const float* Wc_l = (const float*)d_in[13];
    const float* Wc_r = (const float*)d_in[14];
    const float* bc = (const float*)d_in[15];
    const float* Wp_l[2] = {(const float*)d_in[16], (const float*)d_in[19]};
    const float* Wp_r[2] = {(const float*)d_in[17], (const float*)d_in[20]};
    const float* bp[2] = {(const float*)d_in[18], (const float*)d_in[21]};
    const float* W1 = (const float*)d_in[22];
    const float* b1 = (const float*)d_in[23];
    const float* W2 = (const float*)d_in[24];
    const float* b2 = (const float*)d_in[25];
    const float* W3 = (const float*)d_in[26];
    const float* b3 = (const float*)d_in[27];
    const float* Wf = (const float*)d_in[28];
    const float* bf = (const float*)d_in[29];

    char* ws = (char*)d_ws;
    // CSR path layout:
    //  bufA 64MB | bufB 64MB | csr 32MB(E0*4) | off 2MB+pad | part 4KB | sums | scal
    const size_t OFF_CSR = 134217728;
    const size_t OFF_OFF = 167772160;
    const size_t OFF_PART = 169869824;
    const size_t OFF_SUMS = 169873920;
    const size_t OFF_SCAL = 169873952;
    const size_t NEED_CSR = 169874432;

    bool use_csr = ws_size >= NEED_CSR;

    float* bufA = (float*)ws;
    float* bufB = (float*)(ws + 67108864);
    double* sums;
    float* scal;

    float* P = bufA;  // holds previous-level post-tanh result
    float* Q = bufB;
    coarse_kernel<<<1, 64, 0, stream>>>(P, Wc_l, Wc_r, bc);

    if (use_csr) {
        int* csr = (int*)(ws + OFF_CSR);
        int* off = (int*)(ws + OFF_OFF);
        int* part = (int*)(ws + OFF_PART);
        sums = (double*)(ws + OFF_SUMS);
        scal = (float*)(ws + OFF_SCAL);

        for (int l = 5; l >= 0; --l) {
            int n = nl[l], E = El[l];
            gather_kernel<<<imin((n * 32 + 255) / 256, 65536), 256, 0, stream>>>(Q, P, inv[l], n);
            // build CSR for this level (used by both convs)
            hipMemsetAsync(off, 0, (size_t)n * sizeof(int), stream);
            hist_kernel<<<imin((E + 255) / 256, 32768), 256, 0, stream>>>(off, edges[l] + E, E);
            int nb = (n + 1023) / 1024;
            scan1_kernel<<<nb, 1024, 0, stream>>>(off, part, n);
            scan2_kernel<<<1, 1024, 0, stream>>>(part, nb);
            scan3_kernel<<<nb, 1024, 0, stream>>>(off, part, n);
            fill_kernel<<<imin((E + 255) / 256, 32768), 256, 0, stream>>>(off, csr, edges[l], E);
            // conv1: x=Q -> out=P's buffer; conv2: x=out1 -> out=Q's buffer
            conv_csr_kernel<<<imin((n + 7) / 8, 8192), 256, 0, stream>>>(
                P, Q, csr, off, Wp_l[0], Wp_r[0], bp[0], n);
            conv_csr_kernel<<<imin((n + 7) / 8, 8192), 256, 0, stream>>>(
                Q, P, csr, off, Wp_l[1], Wp_r[1], bp[1], n);
            float* t = P; P = Q; Q = t;
        }
    } else {
        // fallback: R2 atomic-scatter path
        float* deg = (float*)(ws + 134217728);
        sums = (double*)(ws + 136314880);
        scal = (float*)(ws + 136315008);
        for (int l = 5; l >= 0; --l) {
            int n = nl[l], E = El[l];
            gather_kernel<<<imin((n * 32 + 255) / 256, 65536), 256, 0, stream>>>(Q, P, inv[l], n);
            hipMemsetAsync(deg, 0, (size_t)n * sizeof(float), stream);
            deg_kernel<<<imin((E + 255) / 256, 32768), 256, 0, stream>>>(deg, edges[l] + E, E);
            invdeg_kernel<<<imin((n + 255) / 256, 8192), 256, 0, stream>>>(deg, n);
            hipMemsetAsync(P, 0, (size_t)n * 32 * sizeof(float), stream);
            scatter_kernel<<<imin((E * 32 + 255) / 256, 65536), 256, 0, stream>>>(P, Q, edges[l], E);
            dense_kernel<<<(n + 7) / 8, 256, 0, stream>>>(P, Q, deg, Wp_l[0], Wp_r[0], bp[0], n);
            hipMemsetAsync(Q, 0, (size_t)n * 32 * sizeof(float), stream);
            scatter_kernel<<<imin((E * 32 + 255) / 256, 65536), 256, 0, stream>>>(Q, P, edges[l], E);
            dense_kernel<<<(n + 7) / 8, 256, 0, stream>>>(Q, P, deg, Wp_l[1], Wp_r[1], bp[1], n);
            float* t = P; P = Q; Q = t;
        }
    }

    hipMemsetAsync(sums, 0, 3 * sizeof(double), stream);
    mlp_kernel<<<4096, 256, 0, stream>>>((float*)d_out, P, W1, b1, W2, b2, W3, b3, Wf, bf,
                                         sums, nl[0]);
    qr_scalar_kernel<<<1, 1, 0, stream>>>(scal, sums, (const float*)d_out);
    q_kernel<<<imin((nl[0] + 255) / 256, 4096), 256, 0, stream>>>((float*)d_out, scal, nl[0]);
}

// Round 7
// 2048.152 us; speedup vs baseline: 2.7383x; 1.2921x over previous
//
#include <hip/hip_runtime.h>
#include <math.h>

// ---------------------------------------------------------------------------
// ModelSpectral: hierarchical SAGEConv unpooling + MLP tail + QR(524288x2).
//
// R3: push-scatter hit the f32-atomic issue ceiling -> CSR pull aggregation.
// R5: conv latency-bound -> 8-way software-pipelined neighbor loop.
// R6: fill_kernel (counting-sort scatter) was 760us: 4B random writes =
//     1 cache line per edge (WRITE_SIZE 526MB for 33MB payload). Replace
//     hist+memset+scan+fill with a 3-phase bucketed build:
//       A) per-block bucket hist (dst>>10, <=512 buckets) -> gh[b][blk]
//       B) exclusive scan of gh -> per-(bucket,block) cursors
//       C) partition edges into part[] (packed (src<<10)|dstlocal,
//          per-(block,bucket) contiguous segments -> coalesced-ish)
//       D) per-bucket local fill: LDS hist+scan of 1024 dsts, write off[]
//          directly and scatter csr within a ~64KB L2-resident window.
//     part/gh/spart live in the DEAD conv1-output buffer (consumed-before-
//     overwrite, stream-ordered) -> ws footprint unchanged.
//
// All conv outputs stored POST-tanh. Falls back to R2 atomic-scatter path
// if ws too small.
// ---------------------------------------------------------------------------

static inline int imin(int a, int b) { return a < b ? a : b; }

__global__ void coarse_kernel(float* __restrict__ out, const float* __restrict__ Wl,
                              const float* __restrict__ Wr, const float* __restrict__ b) {
    int t = threadIdx.x;
    if (t < 64) {
        int i = t >> 5, c = t & 31;
        // x = eye(2); edges [[0,1],[1,0]]: agg[i] = x[1-i], deg=1
        out[i * 32 + c] = tanhf(Wl[(1 ^ i) * 32 + c] + Wr[i * 32 + c] + b[c]);
    }
}

__global__ void gather_kernel(float* __restrict__ out, const float* __restrict__ in,
                              const int* __restrict__ inv, int n) {
    int total = n * 32;
    int stride = gridDim.x * blockDim.x;
    for (int idx = blockIdx.x * blockDim.x + threadIdx.x; idx < total; idx += stride) {
        int i = idx >> 5, j = idx & 31;
        out[idx] = in[inv[i] * 32 + j];
    }
}

// ---------------- bucketed CSR build ----------------
// bucket = dst >> 10 (1024 dsts per bucket), NB = ceil(n/1024) <= 512.

// A: per-block bucket histogram -> gh[b*G + blk]  (bucket-major for scan)
__global__ void bkt_hist_kernel(int* __restrict__ gh, const int* __restrict__ dst,
                                int E, int NB, int G) {
    __shared__ int cnt[512];
    for (int t = threadIdx.x; t < NB; t += blockDim.x) cnt[t] = 0;
    __syncthreads();
    int stride = G * blockDim.x;
    for (int e = blockIdx.x * blockDim.x + threadIdx.x; e < E; e += stride)
        atomicAdd(&cnt[dst[e] >> 10], 1);
    __syncthreads();
    for (int t = threadIdx.x; t < NB; t += blockDim.x) gh[t * G + blockIdx.x] = cnt[t];
}

// exclusive scan, 1024 elems per block (Hillis-Steele in LDS)
__global__ void scan1_kernel(int* __restrict__ a, int* __restrict__ part, int n) {
    __shared__ int s[1024];
    int t = threadIdx.x, i = blockIdx.x * 1024 + t;
    int v = (i < n) ? a[i] : 0;
    s[t] = v;
    __syncthreads();
    for (int off = 1; off < 1024; off <<= 1) {
        int add = (t >= off) ? s[t - off] : 0;
        __syncthreads();
        s[t] += add;
        __syncthreads();
    }
    if (i < n) a[i] = s[t] - v;             // exclusive
    if (t == 1023) part[blockIdx.x] = s[t]; // block total
}

__global__ void scan2_kernel(int* __restrict__ part, int nb) {
    __shared__ int s[1024];
    int t = threadIdx.x;
    int v = (t < nb) ? part[t] : 0;
    s[t] = v;
    __syncthreads();
    for (int off = 1; off < 1024; off <<= 1) {
        int add = (t >= off) ? s[t - off] : 0;
        __syncthreads();
        s[t] += add;
        __syncthreads();
    }
    if (t < nb) part[t] = s[t] - v;         // exclusive
}

__global__ void scan3_kernel(int* __restrict__ a, const int* __restrict__ part, int n) {
    int i = blockIdx.x * 1024 + threadIdx.x;
    if (i < n && blockIdx.x > 0) a[i] += part[blockIdx.x];
}

// C: partition edges into part[]: packed (src<<10)|dst_local.
// gh must be pre-scanned; same grid-stride traversal as bkt_hist.
__global__ void bkt_part_kernel(int* __restrict__ part, const int* __restrict__ gh,
                                const int* __restrict__ edges, int E, int NB, int G) {
    __shared__ int cur[512];
    const int* __restrict__ src = edges;
    const int* __restrict__ dst = edges + E;
    for (int t = threadIdx.x; t < NB; t += blockDim.x) cur[t] = gh[t * G + blockIdx.x];
    __syncthreads();
    int stride = G * blockDim.x;
    for (int e = blockIdx.x * blockDim.x + threadIdx.x; e < E; e += stride) {
        int d = dst[e];
        int b = d >> 10;
        int p = atomicAdd(&cur[b], 1);
        part[p] = (src[e] << 10) | (d & 1023);
    }
}

// D: per-bucket local fill. Writes off[d] (END convention, globally
// consistent: off[d-1] = start of d) and csr[] scattered only within the
// bucket's contiguous ~64KB window (L2-resident).
__global__ void __launch_bounds__(1024)
bkt_fill_kernel(int* __restrict__ csr, int* __restrict__ off,
                const int* __restrict__ part, const int* __restrict__ gh,
                int E, int n, int NB, int G) {
    __shared__ int cnt[1024], s[1024];
    int b = blockIdx.x, t = threadIdx.x;
    int beg = gh[b * G];                          // bucket base (scanned)
    int endp = (b + 1 < NB) ? gh[(b + 1) * G] : E;
    cnt[t] = 0;
    __syncthreads();
    for (int i = beg + t; i < endp; i += 1024)
        atomicAdd(&cnt[part[i] & 1023], 1);
    __syncthreads();
    int v = cnt[t];
    s[t] = v;
    __syncthreads();
    for (int o = 1; o < 1024; o <<= 1) {
        int add = (t >= o) ? s[t - o] : 0;
        __syncthreads();
        s[t] += add;
        __syncthreads();
    }
    int d = b * 1024 + t;
    if (d < n) off[d] = beg + s[t];               // inclusive end of dst d
    cnt[t] = beg + s[t] - v;                      // global start cursor
    __syncthreads();
    for (int i = beg + t; i < endp; i += 1024) {
        int pv = part[i];
        int p = atomicAdd(&cnt[pv & 1023], 1);
        csr[p] = pv >> 10;
    }
}

// fused conv: out[d] = tanh( mean_{s in csr[d]}(x[s]) @ Wl + x[d] @ Wr + b )
// 32 lanes per row (lane = feature), 8 rows per 256-thread block, grid-stride.
// range(d) = [ d? off[d-1] : 0 , off[d] ). Neighbor loop 8-way pipelined.
__global__ void __launch_bounds__(256)
conv_csr_kernel(float* __restrict__ out, const float* __restrict__ x,
                const int* __restrict__ csr, const int* __restrict__ off,
                const float* __restrict__ Wl, const float* __restrict__ Wr,
                const float* __restrict__ b, int n) {
    __shared__ float sWl[1024], sWr[1024], sb[32];
    for (int t = threadIdx.x; t < 1024; t += blockDim.x) { sWl[t] = Wl[t]; sWr[t] = Wr[t]; }
    if (threadIdx.x < 32) sb[threadIdx.x] = b[threadIdx.x];
    __syncthreads();
    int lane = threadIdx.x & 31;
    int grp = threadIdx.x >> 5;
    int rstride = gridDim.x * 8;
    for (int row = blockIdx.x * 8 + grp; row < n; row += rstride) {
        int end = off[row];
        int start = (row == 0) ? 0 : off[row - 1];
        float acc = 0.f;
        int i = start;
        for (; i + 8 <= end; i += 8) {
            int s0 = csr[i + 0], s1 = csr[i + 1], s2 = csr[i + 2], s3 = csr[i + 3];
            int s4 = csr[i + 4], s5 = csr[i + 5], s6 = csr[i + 6], s7 = csr[i + 7];
            float v0 = x[(size_t)s0 * 32 + lane];
            float v1 = x[(size_t)s1 * 32 + lane];
            float v2 = x[(size_t)s2 * 32 + lane];
            float v3 = x[(size_t)s3 * 32 + lane];
            float v4 = x[(size_t)s4 * 32 + lane];
            float v5 = x[(size_t)s5 * 32 + lane];
            float v6 = x[(size_t)s6 * 32 + lane];
            float v7 = x[(size_t)s7 * 32 + lane];
            acc += ((v0 + v1) + (v2 + v3)) + ((v4 + v5) + (v6 + v7));
        }
        for (; i + 2 <= end; i += 2) {
            int s0 = csr[i], s1 = csr[i + 1];
            float v0 = x[(size_t)s0 * 32 + lane];
            float v1 = x[(size_t)s1 * 32 + lane];
            acc += v0 + v1;
        }
        if (i < end) acc += x[(size_t)csr[i] * 32 + lane];

        float am = acc * (1.f / fmaxf((float)(end - start), 1.f));
        float xv = x[(size_t)row * 32 + lane];
        float o = sb[lane];
#pragma unroll
        for (int k = 0; k < 32; ++k) {
            float a = __shfl(am, k, 32);
            float t = __shfl(xv, k, 32);
            o += a * sWl[k * 32 + lane] + t * sWr[k * 32 + lane];
        }
        out[(size_t)row * 32 + lane] = tanhf(o);
    }
}

// ---------------- fallback (R2 atomic-scatter path) ----------------
__global__ void deg_kernel(float* __restrict__ deg, const int* __restrict__ dst, int E) {
    int stride = gridDim.x * blockDim.x;
    for (int e = blockIdx.x * blockDim.x + threadIdx.x; e < E; e += stride)
        unsafeAtomicAdd(&deg[dst[e]], 1.0f);
}

__global__ void invdeg_kernel(float* __restrict__ deg, int n) {
    int stride = gridDim.x * blockDim.x;
    for (int i = blockIdx.x * blockDim.x + threadIdx.x; i < n; i += stride)
        deg[i] = 1.0f / fmaxf(deg[i], 1.0f);
}

__global__ void scatter_kernel(float* __restrict__ agg, const float* __restrict__ x,
                               const int* __restrict__ edges, int E) {
    const int* __restrict__ src = edges;
    const int* __restrict__ dst = edges + E;
    int total = E * 32;
    int stride = gridDim.x * blockDim.x;
    for (int idx = blockIdx.x * blockDim.x + threadIdx.x; idx < total; idx += stride) {
        int e = idx >> 5, j = idx & 31;
        unsafeAtomicAdd(&agg[dst[e] * 32 + j], x[src[e] * 32 + j]);
    }
}

__global__ void dense_kernel(float* __restrict__ agg, const float* __restrict__ x,
                             const float* __restrict__ invdeg,
                             const float* __restrict__ Wl, const float* __restrict__ Wr,
                             const float* __restrict__ b, int n) {
    __shared__ float sWl[1024], sWr[1024], sb[32];
    for (int t = threadIdx.x; t < 1024; t += blockDim.x) { sWl[t] = Wl[t]; sWr[t] = Wr[t]; }
    if (threadIdx.x < 32) sb[threadIdx.x] = b[threadIdx.x];
    __syncthreads();
    int row = blockIdx.x * 8 + (threadIdx.x >> 5);
    int c = threadIdx.x & 31;
    if (row >= n) return;
    float av = agg[row * 32 + c] * invdeg[row];
    float xv = x[row * 32 + c];
    float acc = sb[c];
#pragma unroll
    for (int k = 0; k < 32; ++k) {
        float a = __shfl(av, k, 32);
        float t = __shfl(xv, k, 32);
        acc += a * sWl[k * 32 + c] + t * sWr[k * 32 + c];
    }
    agg[row * 32 + c] = tanhf(acc);
}

// ---------------- MLP tail + QR ----------------
// Wave-parallel fused MLP: 32 lanes per row, lane c owns feature c.
__global__ void __launch_bounds__(256)
mlp_kernel(float* __restrict__ y, const float* __restrict__ x,
           const float* __restrict__ W1, const float* __restrict__ b1,
           const float* __restrict__ W2, const float* __restrict__ b2,
           const float* __restrict__ W3, const float* __restrict__ b3,
           const float* __restrict__ Wf, const float* __restrict__ bf,
           double* __restrict__ sums, int n) {
    __shared__ float sW1[512], sb1[16], sW2[512], sb2[32], sW3[1024], sb3[32], sWf[64], sbf[2];
    for (int t = threadIdx.x; t < 512; t += blockDim.x) { sW1[t] = W1[t]; sW2[t] = W2[t]; }
    for (int t = threadIdx.x; t < 1024; t += blockDim.x) sW3[t] = W3[t];
    if (threadIdx.x < 64) sWf[threadIdx.x] = Wf[threadIdx.x];
    if (threadIdx.x < 16) sb1[threadIdx.x] = b1[threadIdx.x];
    if (threadIdx.x < 32) { sb2[threadIdx.x] = b2[threadIdx.x]; sb3[threadIdx.x] = b3[threadIdx.x]; }
    if (threadIdx.x < 2) sbf[threadIdx.x] = bf[threadIdx.x];
    __syncthreads();

    int lane = threadIdx.x & 31;
    int grp = threadIdx.x >> 5;
    double la = 0.0, lab = 0.0, lb = 0.0;
    int rstride = gridDim.x * 8;
    for (int row = blockIdx.x * 8 + grp; row < n; row += rstride) {
        float xv = x[(size_t)row * 32 + lane];
        float h1 = sb1[lane & 15];
#pragma unroll
        for (int k = 0; k < 32; ++k)
            h1 += __shfl(xv, k, 32) * sW1[k * 16 + (lane & 15)];
        float t1 = tanhf(h1);
        float h2 = sb2[lane];
#pragma unroll
        for (int k = 0; k < 16; ++k)
            h2 += __shfl(t1, k, 32) * sW2[k * 32 + lane];
        float t2 = tanhf(h2);
        float h3 = sb3[lane];
#pragma unroll
        for (int k = 0; k < 32; ++k)
            h3 += __shfl(t2, k, 32) * sW3[k * 32 + lane];
        float t3 = tanhf(h3);
        float p0 = t3 * sWf[lane * 2];
        float p1 = t3 * sWf[lane * 2 + 1];
#pragma unroll
        for (int off = 16; off > 0; off >>= 1) {
            p0 += __shfl_xor(p0, off, 32);
            p1 += __shfl_xor(p1, off, 32);
        }
        if (lane == 0) {
            float y0 = p0 + sbf[0], y1 = p1 + sbf[1];
            y[row * 2] = y0;
            y[row * 2 + 1] = y1;
            la += (double)y0 * (double)y0;
            lab += (double)y0 * (double)y1;
            lb += (double)y1 * (double)y1;
        }
    }
#pragma unroll
    for (int off = 32; off > 0; off >>= 1) {
        la += __shfl_down(la, off);
        lab += __shfl_down(lab, off);
        lb += __shfl_down(lb, off);
    }
    __shared__ double red[4][3];
    int wid = threadIdx.x >> 6;
    if ((threadIdx.x & 63) == 0) { red[wid][0] = la; red[wid][1] = lab; red[wid][2] = lb; }
    __syncthreads();
    if (threadIdx.x == 0) {
        double ta = 0, tb = 0, tc = 0;
        for (int w = 0; w < 4; ++w) { ta += red[w][0]; tb += red[w][1]; tc += red[w][2]; }
        unsafeAtomicAdd(&sums[0], ta);
        unsafeAtomicAdd(&sums[1], tb);
        unsafeAtomicAdd(&sums[2], tc);
    }
}

// LAPACK (geqrf/orgqr) Householder sign convention for 2-column QR.
__global__ void qr_scalar_kernel(float* __restrict__ scal, const double* __restrict__ sums,
                                 const float* __restrict__ y) {
    double saa = sums[0], sab = sums[1], sbb = sums[2];
    double a0 = (double)y[0], b0 = (double)y[1];
    double a1 = (double)y[2], b1v = (double)y[3];
    double na = sqrt(saa);
    double beta1 = (a0 >= 0.0) ? -na : na;       // beta = -sign(alpha)*||a||
    double R12 = sab / beta1;                    // (H1 b)[0] = q1.b
    double v2 = sbb - R12 * R12;                 // ||b - R12 q1||^2
    if (v2 < 0.0) v2 = 0.0;
    double nb = sqrt(v2);
    double denom = a0 - beta1;                   // nonzero: a0 + sign(a0)||a||
    double tau1 = (beta1 - a0) / beta1;
    double u1b = b0 + (sab - a0 * b0) / denom;   // v1 . b  (v1[0]=1)
    double y1h = b1v - tau1 * u1b * (a1 / denom);// (H1 b)[1] -> pivot of reflector 2
    double beta2 = (y1h >= 0.0) ? -nb : nb;
    scal[0] = (float)(1.0 / beta1);
    scal[1] = (float)R12;
    scal[2] = (float)(1.0 / beta2);
}

__global__ void q_kernel(float* __restrict__ y, const float* __restrict__ scal, int n) {
    float invb1 = scal[0], R12 = scal[1], invb2 = scal[2];
    int stride = gridDim.x * blockDim.x;
    float2* p = (float2*)y;
    for (int i = blockIdx.x * blockDim.x + threadIdx.x; i < n; i += stride) {
        float2 v = p[i];
        float qa = v.x * invb1;
        float qb = (v.y - R12 * qa) * invb2;
        p[i] = make_float2(qa, qb);
    }
}

extern "C" void kernel_launch(void* const* d_in, const int* in_sizes, int n_in,
                              void* d_out, int out_size, void* d_ws, size_t ws_size,
                              hipStream_t stream) {
    const int* edges[6];
    const int* inv[6];
    int nl[6], El[6];
    for (int l = 0; l < 6; ++l) {
        edges[l] = (const int*)d_in[2 * l];
        inv[l] = (const int*)d_in[2 * l + 1];
        El[l] = in_sizes[2 * l] / 2;
        nl[l] = in_sizes[2 * l + 1];
    }
    const float* Wc_l = (const float*)d_in[13];
    const float* Wc_r = (const float*)d_in[14];
    const float* bc = (const float*)d_in[15];
    const float* Wp_l[2] = {(const float*)d_in[16], (const float*)d_in[19]};
    const float* Wp_r[2] = {(const float*)d_in[17], (const float*)d_in[20]};
    const float* bp[2] = {(const float*)d_in[18], (const float*)d_in[21]};
    const float* W1 = (const float*)d_in[22];
    const float* b1 = (const float*)d_in[23];
    const float* W2 = (const float*)d_in[24];
    const float* b2 = (const float*)d_in[25];
    const float* W3 = (const float*)d_in[26];
    const float* b3 = (const float*)d_in[27];
    const float* Wf = (const float*)d_in[28];
    const float* bf = (const float*)d_in[29];

    char* ws = (char*)d_ws;
    // layout: bufA 64MB | bufB 64MB | csr 32MB | off 2MB | sums | scal
    // (part/gh/spart live inside the dead conv1-output buffer per level)
    const size_t OFF_CSR = 134217728;
    const size_t OFF_OFF = 167772160;
    const size_t OFF_SUMS = 169873920;
    const size_t OFF_SCAL = 169873952;
    const size_t NEED_CSR = 169874432;

    bool use_csr = ws_size >= NEED_CSR;

    float* bufA = (float*)ws;
    float* bufB = (float*)(ws + 67108864);
    double* sums;
    float* scal;

    float* P = bufA;  // holds previous-level post-tanh result
    float* Q = bufB;
    coarse_kernel<<<1, 64, 0, stream>>>(P, Wc_l, Wc_r, bc);

    if (use_csr) {
        int* csr = (int*)(ws + OFF_CSR);
        int* off = (int*)(ws + OFF_OFF);
        sums = (double*)(ws + OFF_SUMS);
        scal = (float*)(ws + OFF_SCAL);

        for (int l = 5; l >= 0; --l) {
            int n = nl[l], E = El[l];
            int NB = (n + 1023) / 1024;                 // <= 512
            int G = imin(256, (E + 4095) / 4096);       // partition blocks
            gather_kernel<<<imin((n * 32 + 255) / 256, 65536), 256, 0, stream>>>(Q, P, inv[l], n);
            // scratch in the DEAD conv1-output buffer (P): consumed before conv1 writes it
            int* part = (int*)P;
            int* gh = part + E;
            int* spart = gh + NB * G;
            bkt_hist_kernel<<<G, 256, 0, stream>>>(gh, edges[l] + E, E, NB, G);
            int sn = NB * G;
            int nsb = (sn + 1023) / 1024;
            scan1_kernel<<<nsb, 1024, 0, stream>>>(gh, spart, sn);
            scan2_kernel<<<1, 1024, 0, stream>>>(spart, nsb);
            scan3_kernel<<<nsb, 1024, 0, stream>>>(gh, spart, sn);
            bkt_part_kernel<<<G, 256, 0, stream>>>(part, gh, edges[l], E, NB, G);
            bkt_fill_kernel<<<NB, 1024, 0, stream>>>(csr, off, part, gh, E, n, NB, G);
            // conv1: x=Q -> out=P (overwrites part/gh AFTER bkt_fill consumed them)
            conv_csr_kernel<<<imin((n + 7) / 8, 8192), 256, 0, stream>>>(
                P, Q, csr, off, Wp_l[0], Wp_r[0], bp[0], n);
            conv_csr_kernel<<<imin((n + 7) / 8, 8192), 256, 0, stream>>>(
                Q, P, csr, off, Wp_l[1], Wp_r[1], bp[1], n);
            float* t = P; P = Q; Q = t;
        }
    } else {
        // fallback: R2 atomic-scatter path
        float* deg = (float*)(ws + 134217728);
        sums = (double*)(ws + 136314880);
        scal = (float*)(ws + 136315008);
        for (int l = 5; l >= 0; --l) {
            int n = nl[l], E = El[l];
            gather_kernel<<<imin((n * 32 + 255) / 256, 65536), 256, 0, stream>>>(Q, P, inv[l], n);
            hipMemsetAsync(deg, 0, (size_t)n * sizeof(float), stream);
            deg_kernel<<<imin((E + 255) / 256, 32768), 256, 0, stream>>>(deg, edges[l] + E, E);
            invdeg_kernel<<<imin((n + 255) / 256, 8192), 256, 0, stream>>>(deg, n);
            hipMemsetAsync(P, 0, (size_t)n * 32 * sizeof(float), stream);
            scatter_kernel<<<imin((E * 32 + 255) / 256, 65536), 256, 0, stream>>>(P, Q, edges[l], E);
            dense_kernel<<<(n + 7) / 8, 256, 0, stream>>>(P, Q, deg, Wp_l[0], Wp_r[0], bp[0], n);
            hipMemsetAsync(Q, 0, (size_t)n * 32 * sizeof(float), stream);
            scatter_kernel<<<imin((E * 32 + 255) / 256, 65536), 256, 0, stream>>>(Q, P, edges[l], E);
            dense_kernel<<<(n + 7) / 8, 256, 0, stream>>>(Q, P, deg, Wp_l[1], Wp_r[1], bp[1], n);
            float* t = P; P = Q; Q = t;
        }
    }

    hipMemsetAsync(sums, 0, 3 * sizeof(double), stream);
    mlp_kernel<<<4096, 256, 0, stream>>>((float*)d_out, P, W1, b1, W2, b2, W3, b3, Wf, bf,
                                         sums, nl[0]);
    qr_scalar_kernel<<<1, 1, 0, stream>>>(scal, sums, (const float*)d_out);
    q_kernel<<<imin((nl[0] + 255) / 256, 4096), 256, 0, stream>>>((float*)d_out, scal, nl[0]);
}